// Round 1
// baseline (113.791 us; speedup 1.0000x reference)
//
#include <hip/hip_runtime.h>
#include <math.h>

#define BATCH 256
#define NHALF 2048      // rows per half
#define DIN 3
#define DK 64
#define SPLIT 4
#define ROWS_PER_BLOCK (NHALF / SPLIT)      // 512
#define ROWS_PER_WAVE  (ROWS_PER_BLOCK / 4) // 128

// Kernel 1: per (b, half, slice) block, accumulate
//   accq[k]  = sum_n softmax_k(x Wq + bq)[n,k]
//   ek[k]    = sum_n exp((x Wk + bk)[n,k])
//   ekv[k,v] = sum_n exp((x Wk + bk)[n,k]) * (x Wv + bv)[n,v]
// Layout: each wave handles 4 rows at a time; 16 lanes per row; each lane owns
// k = sub + 16*j for j in 0..3. Row softmax = local sum + 4-step shfl_xor
// within the 16-lane group. Column softmax stays in registers.
__global__ __launch_bounds__(256) void ea_partial(
    const float* __restrict__ inp,
    const float* __restrict__ Wq, const float* __restrict__ bq,
    const float* __restrict__ Wk, const float* __restrict__ bk,
    const float* __restrict__ Wv, const float* __restrict__ bv,
    float* __restrict__ ws)
{
    const int blk   = blockIdx.x;
    const int b     = blk / (2 * SPLIT);
    const int rem   = blk % (2 * SPLIT);
    const int half  = rem / SPLIT;
    const int slice = rem % SPLIT;

    const int tid  = threadIdx.x;
    const int w    = tid >> 6;   // wave 0..3
    const int lane = tid & 63;
    const int g    = lane >> 4;  // row-group 0..3 within wave
    const int sub  = lane & 15;  // lane within row-group

    // per-lane weights for k = sub + 16*j
    float wq0[4], wq1[4], wq2[4], bqv[4];
    float wk0[4], wk1[4], wk2[4], bkv[4];
#pragma unroll
    for (int j = 0; j < 4; ++j) {
        int k = sub + 16 * j;
        wq0[j] = Wq[0 * DK + k]; wq1[j] = Wq[1 * DK + k]; wq2[j] = Wq[2 * DK + k];
        bqv[j] = bq[k];
        wk0[j] = Wk[0 * DK + k]; wk1[j] = Wk[1 * DK + k]; wk2[j] = Wk[2 * DK + k];
        bkv[j] = bk[k];
    }
    float wv[9], bvv[3];
#pragma unroll
    for (int i = 0; i < 9; ++i) wv[i] = Wv[i];
#pragma unroll
    for (int i = 0; i < 3; ++i) bvv[i] = bv[i];

    float accq[4] = {0.f, 0.f, 0.f, 0.f};
    float ek[4]   = {0.f, 0.f, 0.f, 0.f};
    float ekv[4][3] = {{0.f,0.f,0.f},{0.f,0.f,0.f},{0.f,0.f,0.f},{0.f,0.f,0.f}};

    const float* xbase = inp + ((size_t)b * (2 * NHALF) + (size_t)half * NHALF) * DIN;
    const int row0 = slice * ROWS_PER_BLOCK + w * ROWS_PER_WAVE;

    for (int i = 0; i < ROWS_PER_WAVE; i += 4) {
        const int row = row0 + i + g;
        const float* xp = xbase + (size_t)row * DIN;
        const float x0 = xp[0], x1 = xp[1], x2 = xp[2];

        // v = x @ Wv + bv  (Wv stored [in,out]: v[j] = sum_d x[d]*Wv[d*3+j] + bv[j])
        const float v0 = fmaf(x0, wv[0], fmaf(x1, wv[3], fmaf(x2, wv[6], bvv[0])));
        const float v1 = fmaf(x0, wv[1], fmaf(x1, wv[4], fmaf(x2, wv[7], bvv[1])));
        const float v2 = fmaf(x0, wv[2], fmaf(x1, wv[5], fmaf(x2, wv[8], bvv[2])));

        // q logits -> exp, row softmax over all 64 k (16 lanes x 4 j)
        float eq[4];
        float rowsum = 0.f;
#pragma unroll
        for (int j = 0; j < 4; ++j) {
            float sq = fmaf(x0, wq0[j], fmaf(x1, wq1[j], fmaf(x2, wq2[j], bqv[j])));
            eq[j] = __expf(sq);
            rowsum += eq[j];
        }
        rowsum += __shfl_xor(rowsum, 1);
        rowsum += __shfl_xor(rowsum, 2);
        rowsum += __shfl_xor(rowsum, 4);
        rowsum += __shfl_xor(rowsum, 8);
        const float inv = __builtin_amdgcn_rcpf(rowsum);

#pragma unroll
        for (int j = 0; j < 4; ++j) {
            accq[j] = fmaf(eq[j], inv, accq[j]);
            float sk = fmaf(x0, wk0[j], fmaf(x1, wk1[j], fmaf(x2, wk2[j], bkv[j])));
            float e = __expf(sk);
            ek[j] += e;
            ekv[j][0] = fmaf(e, v0, ekv[j][0]);
            ekv[j][1] = fmaf(e, v1, ekv[j][1]);
            ekv[j][2] = fmaf(e, v2, ekv[j][2]);
        }
    }

    // block reduction of 16 partial sets (4 waves x 4 groups), stride 321 to
    // avoid 16-way bank conflict on the stride-320 column read.
    __shared__ float lds[16][321];
    const int slot = w * 4 + g;
#pragma unroll
    for (int j = 0; j < 4; ++j) {
        int k = sub + 16 * j;
        lds[slot][k]        = accq[j];
        lds[slot][64 + k]   = ek[j];
        lds[slot][128 + k]  = ekv[j][0];
        lds[slot][192 + k]  = ekv[j][1];
        lds[slot][256 + k]  = ekv[j][2];
    }
    __syncthreads();

    float* outp = ws + (size_t)blk * 320;
    for (int idx = tid; idx < 320; idx += 256) {
        float s = 0.f;
#pragma unroll
        for (int p = 0; p < 16; ++p) s += lds[p][idx];
        outp[idx] = s;
    }
}

// Kernel 2: one block (64 threads) per b. Sum the SPLIT slices, form
// out_h[v] = sum_k (accq[k]/N) * ekv[k][v]/ek[k], combine halves, L2-normalize.
__global__ __launch_bounds__(64) void ea_final(
    const float* __restrict__ ws, float* __restrict__ out)
{
    const int b = blockIdx.x;
    const int lane = threadIdx.x;  // = k

    float res[2][3];
#pragma unroll
    for (int h = 0; h < 2; ++h) {
        float accq = 0.f, ek = 0.f, e0 = 0.f, e1 = 0.f, e2 = 0.f;
#pragma unroll
        for (int s = 0; s < SPLIT; ++s) {
            const float* p = ws + (size_t)((b * 2 + h) * SPLIT + s) * 320;
            accq += p[lane];
            ek   += p[64 + lane];
            e0   += p[128 + lane];
            e1   += p[192 + lane];
            e2   += p[256 + lane];
        }
        const float mq = accq * (1.0f / (float)NHALF);
        const float r  = mq / ek;
        float p0 = r * e0, p1 = r * e1, p2 = r * e2;
        for (int m = 1; m < 64; m <<= 1) {
            p0 += __shfl_xor(p0, m);
            p1 += __shfl_xor(p1, m);
            p2 += __shfl_xor(p2, m);
        }
        res[h][0] = p0; res[h][1] = p1; res[h][2] = p2;
    }

    const float a0 = 0.5f * (res[0][0] + res[1][0]);
    const float a1 = 0.5f * (res[0][1] + res[1][1]);
    const float a2 = 0.5f * (res[0][2] + res[1][2]);
    const float nrm = rsqrtf(a0 * a0 + a1 * a1 + a2 * a2);
    if (lane == 0) {
        out[(size_t)b * 3 + 0] = a0 * nrm;
        out[(size_t)b * 3 + 1] = a1 * nrm;
        out[(size_t)b * 3 + 2] = a2 * nrm;
    }
}

extern "C" void kernel_launch(void* const* d_in, const int* in_sizes, int n_in,
                              void* d_out, int out_size, void* d_ws, size_t ws_size,
                              hipStream_t stream) {
    const float* inp = (const float*)d_in[0];
    const float* Wq  = (const float*)d_in[1];
    const float* bq  = (const float*)d_in[2];
    const float* Wk  = (const float*)d_in[3];
    const float* bk  = (const float*)d_in[4];
    const float* Wv  = (const float*)d_in[5];
    const float* bv  = (const float*)d_in[6];
    float* ws  = (float*)d_ws;
    float* out = (float*)d_out;

    hipLaunchKernelGGL(ea_partial, dim3(BATCH * 2 * SPLIT), dim3(256), 0, stream,
                       inp, Wq, bq, Wk, bk, Wv, bv, ws);
    hipLaunchKernelGGL(ea_final, dim3(BATCH), dim3(64), 0, stream, ws, out);
}